// Round 4
// baseline (6549.460 us; speedup 1.0000x reference)
//
#include <hip/hip_runtime.h>
#include <cstddef>
#include <cstdint>

#define BB 64
#define TT 4096
#define HD 64
#define FP 72  // padded f16 feature stride (144B rows -> 9 LDS granules, conflict-free)

typedef _Float16 f16;
typedef _Float16 f16x8 __attribute__((ext_vector_type(8)));
typedef _Float16 f16x4 __attribute__((ext_vector_type(4)));
typedef float f32x4 __attribute__((ext_vector_type(4)));

__device__ __forceinline__ float sigf(float v) { return 1.0f / (1.0f + __expf(-v)); }
__device__ __forceinline__ float tanhf_fast(float v) { return 1.0f - 2.0f / (__expf(2.0f * v) + 1.0f); }

// ---------------------------------------------------------------------------
// Stats pass 1: 256 blocks = (batch b = blk>>2, T-segment seg = blk&3).
// ---------------------------------------------------------------------------
__global__ __launch_bounds__(256) void stats_part(const float* __restrict__ x,
                                                  float* __restrict__ part) {
    const int b = blockIdx.x >> 2, seg = blockIdx.x & 3;
    const int f = threadIdx.x & 63, grp = threadIdx.x >> 6;
    const float* xb = x + (size_t)b * TT * HD + (size_t)seg * (TT / 4) * HD;
    float s = 0.f, s2 = 0.f;
    for (int t = grp; t < TT / 4; t += 4) {
        float v = xb[t * HD + f];
        s += v;
        s2 = fmaf(v, v, s2);
    }
    __shared__ float ls[4][64];
    __shared__ float ls2[4][64];
    ls[grp][f] = s;
    ls2[grp][f] = s2;
    __syncthreads();
    if (threadIdx.x < 64) {
        float ss = 0.f, ss2 = 0.f;
#pragma unroll
        for (int i = 0; i < 4; ++i) { ss += ls[i][f]; ss2 += ls2[i][f]; }
        part[blockIdx.x * HD + f] = ss;
        part[256 * HD + blockIdx.x * HD + f] = ss2;
    }
}

__global__ __launch_bounds__(64) void stats_fin(const float* __restrict__ part,
                                                float* __restrict__ stats) {
    const int b = blockIdx.x, f = threadIdx.x;
    float s = 0.f, s2 = 0.f;
#pragma unroll
    for (int seg = 0; seg < 4; ++seg) {
        s += part[(b * 4 + seg) * HD + f];
        s2 += part[256 * HD + (b * 4 + seg) * HD + f];
    }
    float mu = s * (1.0f / TT);
    float var = s2 * (1.0f / TT) - mu * mu;
    stats[b * HD + f] = mu;
    stats[BB * HD + b * HD + f] = rsqrtf(var + 1e-5f);
}

// ---------------------------------------------------------------------------
// MFMA recurrent kernel. 4 blocks x 16 batches, 512 threads (8 waves).
// Transposed gates: G^T[16b x 256r] = h^T[16b x 64f] . W^T[64f x 256r].
// Waves 0-3: layer-1 gates(t)  (A-ops: hT0=h0(t), hT1=h1(t-1))
// Waves 4-7: layer-0 gates(t+1)(A-ops: hT0=h0(t), xn(t+1))
// Wave w tile set {w,w+4,w+8,w+12}: lane l owns feature 16w+(l&15), all 4
// gate types (one per tile), batches 4*(l>>4)..+4 (D regs r=0..3). c-state
// in lane registers; updates wave-local; ONE barrier per step.
// ---------------------------------------------------------------------------
__global__ __launch_bounds__(512, 2) void rnn_mfma(
    const float* __restrict__ x,
    const float* __restrict__ Wih0, const float* __restrict__ Whh0,
    const float* __restrict__ bih0, const float* __restrict__ bhh0,
    const float* __restrict__ Wih1, const float* __restrict__ Whh1,
    const float* __restrict__ bih1, const float* __restrict__ bhh1,
    const float* __restrict__ stats,
    float* __restrict__ h1out) {
    const int blk = blockIdx.x;
    const int tid = threadIdx.x;
    const int lane = tid & 63;
    const int wid = tid >> 6;
    const bool L1w = (wid < 4);
    const int wq = L1w ? wid : (wid - 4);
    const int ln15 = lane & 15;
    const int l16 = lane >> 4;

    __shared__ __align__(16) f16 hT0[2][16 * FP];     // h0 ping-pong [batch][feat]
    __shared__ __align__(16) f16 hT1[16][16 * FP];    // h1 ring (slot = t&15)
    __shared__ __align__(16) f16 xnb[2][8][16 * FP];  // xn chunk dbuf [par][tau]

    // ---- static weight B-fragments (f16), 16 x f16x8 per wave ----
    const float* WA = L1w ? Wih1 : Whh0;   // pairs with A = hT0
    const float* WBm = L1w ? Whh1 : Wih0;  // pairs with A = hT1 / xn
    f16x8 wA[4][2], wB[4][2];
#pragma unroll
    for (int i = 0; i < 4; ++i) {
        const int row = 16 * (wq + 4 * i) + ln15;
#pragma unroll
        for (int kt = 0; kt < 2; ++kt) {
            const int fb = 32 * kt + 8 * l16;
            const float4 a0 = *(const float4*)&WA[row * HD + fb];
            const float4 a1 = *(const float4*)&WA[row * HD + fb + 4];
            const float4 b0 = *(const float4*)&WBm[row * HD + fb];
            const float4 b1 = *(const float4*)&WBm[row * HD + fb + 4];
            wA[i][kt] = (f16x8){(f16)a0.x, (f16)a0.y, (f16)a0.z, (f16)a0.w,
                                (f16)a1.x, (f16)a1.y, (f16)a1.z, (f16)a1.w};
            wB[i][kt] = (f16x8){(f16)b0.x, (f16)b0.y, (f16)b0.z, (f16)b0.w,
                                (f16)b1.x, (f16)b1.y, (f16)b1.z, (f16)b1.w};
        }
    }

    const int phi = 16 * wq + ln15;  // feature owned by this lane
    const float* bi = L1w ? bih1 : bih0;
    const float* bh = L1w ? bhh1 : bhh0;
    float bias[4];
#pragma unroll
    for (int i = 0; i < 4; ++i) bias[i] = bi[64 * i + phi] + bh[64 * i + phi];

    // ---- staging / flush mapping: thread = (batch sb, feat-quad sq, tau-hi) ----
    const int sb = tid >> 5;
    const int sq = (tid >> 1) & 15;
    const int sth = tid & 1;
    const size_t gb = (size_t)blk * 16 + sb;
    const float4 mu4 = *(const float4*)&stats[gb * HD + 4 * sq];
    const float4 rs4 = *(const float4*)&stats[(size_t)BB * HD + gb * HD + 4 * sq];
    const float* xrow = x + gb * TT * HD;
    float* orow = h1out + gb * TT * HD;

    // zero hT0 (both) and hT1 (all slots; slot 15 is h1(-1)=0)
    for (int i = tid; i < 2 * 16 * FP / 2; i += 512) ((unsigned*)hT0)[i] = 0u;
    for (int i = tid; i < 16 * 16 * FP / 2; i += 512) ((unsigned*)hT1)[i] = 0u;

    // stage chunk 0 directly
#pragma unroll
    for (int i = 0; i < 4; ++i) {
        const int tau = sth * 4 + i;
        float4 v = *(const float4*)&xrow[(size_t)tau * HD + 4 * sq];
        f16x4 h4 = {(f16)((v.x - mu4.x) * rs4.x), (f16)((v.y - mu4.y) * rs4.y),
                    (f16)((v.z - mu4.z) * rs4.z), (f16)((v.w - mu4.w) * rs4.w)};
        *(f16x4*)&xnb[0][tau][sb * FP + 4 * sq] = h4;
    }

    float cst[4] = {0.f, 0.f, 0.f, 0.f};

    auto PHASE = [&](int t) {
        // phase 1: A-frags from LDS, 16 MFMAs into 4 tile accumulators
        f16x8 A0[2], A1[2];
        {
            const f16* base = &hT0[t & 1][ln15 * FP + 8 * l16];
            A0[0] = *(const f16x8*)(base);
            A0[1] = *(const f16x8*)(base + 32);
        }
        {
            const f16* bb2 = L1w ? &hT1[(t + 15) & 15][0]
                                 : &xnb[((t + 1) >> 3) & 1][(t + 1) & 7][0];
            const f16* base = bb2 + ln15 * FP + 8 * l16;
            A1[0] = *(const f16x8*)(base);
            A1[1] = *(const f16x8*)(base + 32);
        }
        f32x4 acc[4];
#pragma unroll
        for (int i = 0; i < 4; ++i) {
            acc[i] = (f32x4){0.f, 0.f, 0.f, 0.f};
            acc[i] = __builtin_amdgcn_mfma_f32_16x16x32_f16(A0[0], wA[i][0], acc[i], 0, 0, 0);
            acc[i] = __builtin_amdgcn_mfma_f32_16x16x32_f16(A0[1], wA[i][1], acc[i], 0, 0, 0);
            acc[i] = __builtin_amdgcn_mfma_f32_16x16x32_f16(A1[0], wB[i][0], acc[i], 0, 0, 0);
            acc[i] = __builtin_amdgcn_mfma_f32_16x16x32_f16(A1[1], wB[i][1], acc[i], 0, 0, 0);
        }
        // phase 2: wave-local activations + cell update + h write (f16)
        f16* dest = L1w ? &hT1[t & 15][0] : &hT0[(t + 1) & 1][0];
#pragma unroll
        for (int r = 0; r < 4; ++r) {
            float ai = sigf(acc[0][r] + bias[0]);
            float af = sigf(acc[1][r] + bias[1]);
            float ag = tanhf_fast(acc[2][r] + bias[2]);
            float ao = sigf(acc[3][r] + bias[3]);
            float c = fmaf(af, cst[r], ai * ag);
            cst[r] = c;
            float h = ao * tanhf_fast(c);
            dest[(4 * l16 + r) * FP + phi] = (f16)h;
        }
    };

    __syncthreads();
    if (!L1w) PHASE(-1);  // layer-0 step 0 (hT0[1] zeros, xn(0)); writes hT0[0]
    __syncthreads();

    float4 xr[4];
    for (int t = 0; t < TT; ++t) {
        const int tc = t & 7;
        const int cn = (t >> 3) + 1;
        // issue next chunk's global loads early
        if (tc == 0 && cn < 512) {
#pragma unroll
            for (int i = 0; i < 4; ++i)
                xr[i] = *(const float4*)&xrow[(size_t)(cn * 8 + sth * 4 + i) * HD + 4 * sq];
        }
        PHASE(t);
        // mid-chunk: normalize + LDS-write next chunk (read 2+ barriers later)
        if (tc == 5 && cn < 512) {
#pragma unroll
            for (int i = 0; i < 4; ++i) {
                const int tau = sth * 4 + i;
                f16x4 h4 = {(f16)((xr[i].x - mu4.x) * rs4.x), (f16)((xr[i].y - mu4.y) * rs4.y),
                            (f16)((xr[i].z - mu4.z) * rs4.z), (f16)((xr[i].w - mu4.w) * rs4.w)};
                *(f16x4*)&xnb[cn & 1][tau][sb * FP + 4 * sq] = h4;
            }
        }
        // flush previous chunk's h1 ring slots to global (stable 4+ steps)
        if (tc == 3 && t >= 11) {
            const int fch = (t >> 3) - 1;
            const int sbase = (fch & 1) * 8;
#pragma unroll
            for (int i = 0; i < 4; ++i) {
                const int tau = sth * 4 + i;
                f16x4 hv = *(const f16x4*)&hT1[sbase + tau][sb * FP + 4 * sq];
                float4 o = {(float)hv[0], (float)hv[1], (float)hv[2], (float)hv[3]};
                *(float4*)&orow[(size_t)(fch * 8 + tau) * HD + 4 * sq] = o;
            }
        }
        __syncthreads();
    }
    // epilogue: flush final chunk (slots 8..15 = t 4088..4095)
#pragma unroll
    for (int i = 0; i < 4; ++i) {
        const int tau = sth * 4 + i;
        f16x4 hv = *(const f16x4*)&hT1[8 + tau][sb * FP + 4 * sq];
        float4 o = {(float)hv[0], (float)hv[1], (float)hv[2], (float)hv[3]};
        *(float4*)&orow[(size_t)(511 * 8 + tau) * HD + 4 * sq] = o;
    }
}

// ---------------------------------------------------------------------------
// FC + bias + residual, in place on d_out (hout holds h1, rewritten as out).
// ---------------------------------------------------------------------------
__global__ __launch_bounds__(256) void fc_res(float* __restrict__ hout,
                                              const float* __restrict__ x,
                                              const float* __restrict__ Wfc,
                                              const float* __restrict__ bfc) {
    __shared__ __align__(16) float wfc_lds[HD * HD];
    __shared__ float bfc_lds[HD];
    const int tid = threadIdx.x;
#pragma unroll
    for (int i = 0; i < 4; ++i)
        ((float4*)wfc_lds)[tid + 256 * i] = ((const float4*)Wfc)[tid + 256 * i];
    if (tid < HD) bfc_lds[tid] = bfc[tid];

    const size_t row = (size_t)blockIdx.x * 256 + tid;
    float hr[HD];
    {
        const float4* hp = (const float4*)(hout + row * HD);
#pragma unroll
        for (int i = 0; i < 16; ++i) {
            float4 v = hp[i];
            hr[4 * i] = v.x; hr[4 * i + 1] = v.y;
            hr[4 * i + 2] = v.z; hr[4 * i + 3] = v.w;
        }
    }
    __syncthreads();

    const float4* xp = (const float4*)(x + row * HD);
    float4* op = (float4*)(hout + row * HD);
    for (int j4 = 0; j4 < 16; ++j4) {
        float s0 = 0.f, s1 = 0.f, s2 = 0.f, s3 = 0.f;
        const float* w0 = &wfc_lds[(4 * j4 + 0) * HD];
        const float* w1 = &wfc_lds[(4 * j4 + 1) * HD];
        const float* w2 = &wfc_lds[(4 * j4 + 2) * HD];
        const float* w3 = &wfc_lds[(4 * j4 + 3) * HD];
#pragma unroll
        for (int k = 0; k < HD; ++k) {
            s0 = fmaf(w0[k], hr[k], s0);
            s1 = fmaf(w1[k], hr[k], s1);
            s2 = fmaf(w2[k], hr[k], s2);
            s3 = fmaf(w3[k], hr[k], s3);
        }
        float4 xv = xp[j4];
        float4 o;
        o.x = s0 + bfc_lds[4 * j4 + 0] + xv.x;
        o.y = s1 + bfc_lds[4 * j4 + 1] + xv.y;
        o.z = s2 + bfc_lds[4 * j4 + 2] + xv.z;
        o.w = s3 + bfc_lds[4 * j4 + 3] + xv.w;
        op[j4] = o;
    }
}

// ---------------------------------------------------------------------------
extern "C" void kernel_launch(void* const* d_in, const int* in_sizes, int n_in,
                              void* d_out, int out_size, void* d_ws, size_t ws_size,
                              hipStream_t stream) {
    const float* x    = (const float*)d_in[0];
    const float* Wih0 = (const float*)d_in[1];
    const float* Whh0 = (const float*)d_in[2];
    const float* bih0 = (const float*)d_in[3];
    const float* bhh0 = (const float*)d_in[4];
    const float* Wih1 = (const float*)d_in[5];
    const float* Whh1 = (const float*)d_in[6];
    const float* bih1 = (const float*)d_in[7];
    const float* bhh1 = (const float*)d_in[8];
    const float* Wfc  = (const float*)d_in[9];
    const float* bfc  = (const float*)d_in[10];

    float* part  = (float*)d_ws;                 // 2*256*64 floats = 128 KiB
    float* stats = part + 2 * 256 * HD;          // 2*64*64 floats  =  32 KiB
    float* out   = (float*)d_out;

    stats_part<<<256, 256, 0, stream>>>(x, part);
    stats_fin<<<64, 64, 0, stream>>>(part, stats);
    rnn_mfma<<<4, 512, 0, stream>>>(x, Wih0, Whh0, bih0, bhh0,
                                    Wih1, Whh1, bih1, bhh1, stats, out);
    fc_res<<<1024, 256, 0, stream>>>(out, x, Wfc, bfc);
}

// Round 6
// 3810.033 us; speedup vs baseline: 1.7190x; 1.7190x over previous
//
#include <hip/hip_runtime.h>
#include <cstddef>
#include <cstdint>

#define BB 64
#define TT 4096
#define HD 64
#define FP 72  // f16 feature stride: 144B = 9 x 16B granules -> uniform bank spread

typedef _Float16 f16;
typedef _Float16 f16x8 __attribute__((ext_vector_type(8)));
typedef _Float16 f16x4 __attribute__((ext_vector_type(4)));
typedef float f32x4 __attribute__((ext_vector_type(4)));

__device__ __forceinline__ float sigf(float v) {
    return __builtin_amdgcn_rcpf(1.0f + __builtin_amdgcn_exp2f(-1.44269504f * v));
}
__device__ __forceinline__ float tanhf_fast(float v) {
    return 1.0f - 2.0f * __builtin_amdgcn_rcpf(__builtin_amdgcn_exp2f(2.88539008f * v) + 1.0f);
}

// ---------------------------------------------------------------------------
// Stats pass 1: 256 blocks = (batch b = blk>>2, T-segment seg = blk&3).
// ---------------------------------------------------------------------------
__global__ __launch_bounds__(256) void stats_part(const float* __restrict__ x,
                                                  float* __restrict__ part) {
    const int b = blockIdx.x >> 2, seg = blockIdx.x & 3;
    const int f = threadIdx.x & 63, grp = threadIdx.x >> 6;
    const float* xb = x + (size_t)b * TT * HD + (size_t)seg * (TT / 4) * HD;
    float s = 0.f, s2 = 0.f;
    for (int t = grp; t < TT / 4; t += 4) {
        float v = xb[t * HD + f];
        s += v;
        s2 = fmaf(v, v, s2);
    }
    __shared__ float ls[4][64];
    __shared__ float ls2[4][64];
    ls[grp][f] = s;
    ls2[grp][f] = s2;
    __syncthreads();
    if (threadIdx.x < 64) {
        float ss = 0.f, ss2 = 0.f;
#pragma unroll
        for (int i = 0; i < 4; ++i) { ss += ls[i][f]; ss2 += ls2[i][f]; }
        part[blockIdx.x * HD + f] = ss;
        part[256 * HD + blockIdx.x * HD + f] = ss2;
    }
}

__global__ __launch_bounds__(64) void stats_fin(const float* __restrict__ part,
                                                float* __restrict__ stats) {
    const int b = blockIdx.x, f = threadIdx.x;
    float s = 0.f, s2 = 0.f;
#pragma unroll
    for (int seg = 0; seg < 4; ++seg) {
        s += part[(b * 4 + seg) * HD + f];
        s2 += part[256 * HD + (b * 4 + seg) * HD + f];
    }
    float mu = s * (1.0f / TT);
    float var = s2 * (1.0f / TT) - mu * mu;
    stats[b * HD + f] = mu;
    stats[BB * HD + b * HD + f] = rsqrtf(var + 1e-5f);
}

// ---------------------------------------------------------------------------
// MFMA recurrent kernel, orientation G = W.h :
//   A-frag = weight tile (AGPR-resident via scalar asm moves), B-frag = h
//   (LDS, [batch][feat]). C tile [16 W-rows x 16 batches]: lane holds
//   batch=lane&15, W-row-sub 4*(lane>>4)+r.
// Wave wq owns tiles {64i+16wq}: all 4 gate types for feats 16wq+4*l16+r ->
// cell update lane-local, h written as ONE 8B ds_write of 4 contiguous f16.
// Waves 0-3: layer1 gates(t); waves 4-7: layer0 gates(t+1). 1 barrier/step.
// 4 blocks x 16 batches.
// ---------------------------------------------------------------------------
__global__ __launch_bounds__(512, 2) void rnn_mfma(
    const float* __restrict__ x,
    const float* __restrict__ Wih0, const float* __restrict__ Whh0,
    const float* __restrict__ bih0, const float* __restrict__ bhh0,
    const float* __restrict__ Wih1, const float* __restrict__ Whh1,
    const float* __restrict__ bih1, const float* __restrict__ bhh1,
    const float* __restrict__ stats,
    float* __restrict__ h1out) {
    const int blk = blockIdx.x;
    const int tid = threadIdx.x;
    const int lane = tid & 63;
    const int wid = tid >> 6;
    const bool L1w = (wid < 4);
    const int wq = wid & 3;
    const int ln15 = lane & 15;
    const int l16 = lane >> 4;

    __shared__ __align__(16) f16 hT0[2][16 * FP];     // h0 ping-pong [batch][feat]
    __shared__ __align__(16) f16 hT1[16][16 * FP];    // h1 ring (slot = t&15)
    __shared__ __align__(16) f16 xnb[2][8][16 * FP];  // xn chunk dbuf

    // ---- weight A-fragments: lane = (row-sub ln15, k-block l16) ----
    const float* WA = L1w ? Wih1 : Whh0;   // multiplies h0(t)
    const float* WBm = L1w ? Whh1 : Wih0;  // multiplies h1(t-1) / xn(t+1)

    // Load + convert -> 4 dwords per fragment, then move each dword into an
    // AGPR via scalar untied asm. The asm-volatile defs are non-remat'able,
    // so the weights CANNOT be re-fetched from memory inside the loop.
    uint32_t aA[4][2][4], aB[4][2][4];
#pragma unroll
    for (int i = 0; i < 4; ++i) {
        const int row = 64 * i + 16 * wq + ln15;
#pragma unroll
        for (int kt = 0; kt < 2; ++kt) {
            const int fb = 32 * kt + 8 * l16;
            const float4 a0 = *(const float4*)&WA[row * HD + fb];
            const float4 a1 = *(const float4*)&WA[row * HD + fb + 4];
            const float4 b0 = *(const float4*)&WBm[row * HD + fb];
            const float4 b1 = *(const float4*)&WBm[row * HD + fb + 4];
            f16x8 ha = {(f16)a0.x, (f16)a0.y, (f16)a0.z, (f16)a0.w,
                        (f16)a1.x, (f16)a1.y, (f16)a1.z, (f16)a1.w};
            f16x8 hb = {(f16)b0.x, (f16)b0.y, (f16)b0.z, (f16)b0.w,
                        (f16)b1.x, (f16)b1.y, (f16)b1.z, (f16)b1.w};
            uint4 ua = __builtin_bit_cast(uint4, ha);
            uint4 ub = __builtin_bit_cast(uint4, hb);
            asm volatile("v_accvgpr_write_b32 %0, %1" : "=a"(aA[i][kt][0]) : "v"(ua.x));
            asm volatile("v_accvgpr_write_b32 %0, %1" : "=a"(aA[i][kt][1]) : "v"(ua.y));
            asm volatile("v_accvgpr_write_b32 %0, %1" : "=a"(aA[i][kt][2]) : "v"(ua.z));
            asm volatile("v_accvgpr_write_b32 %0, %1" : "=a"(aA[i][kt][3]) : "v"(ua.w));
            asm volatile("v_accvgpr_write_b32 %0, %1" : "=a"(aB[i][kt][0]) : "v"(ub.x));
            asm volatile("v_accvgpr_write_b32 %0, %1" : "=a"(aB[i][kt][1]) : "v"(ub.y));
            asm volatile("v_accvgpr_write_b32 %0, %1" : "=a"(aB[i][kt][2]) : "v"(ub.z));
            asm volatile("v_accvgpr_write_b32 %0, %1" : "=a"(aB[i][kt][3]) : "v"(ub.w));
        }
    }
    // rebuild fragments (loop-invariant SSA; sourced from AGPR-class values)
    f16x8 wAf[4][2], wBf[4][2];
#pragma unroll
    for (int i = 0; i < 4; ++i)
#pragma unroll
        for (int kt = 0; kt < 2; ++kt) {
            uint4 ua = {aA[i][kt][0], aA[i][kt][1], aA[i][kt][2], aA[i][kt][3]};
            uint4 ub = {aB[i][kt][0], aB[i][kt][1], aB[i][kt][2], aB[i][kt][3]};
            wAf[i][kt] = __builtin_bit_cast(f16x8, ua);
            wBf[i][kt] = __builtin_bit_cast(f16x8, ub);
        }

    // bias folded into accumulator init: acc row-sub = 4*l16+r
    const float* bi = L1w ? bih1 : bih0;
    const float* bh = L1w ? bhh1 : bhh0;
    f32x4 bias[4];
#pragma unroll
    for (int i = 0; i < 4; ++i)
#pragma unroll
        for (int r = 0; r < 4; ++r) {
            const int row = 64 * i + 16 * wq + 4 * l16 + r;
            bias[i][r] = bi[row] + bh[row];
        }

    // staging / flush mapping: thread = (batch sb, feat-quad sq, tau-half sth)
    const int sb = tid >> 5;
    const int sq = (tid >> 1) & 15;
    const int sth = tid & 1;
    const size_t gb = (size_t)blk * 16 + sb;
    const float4 mu4 = *(const float4*)&stats[gb * HD + 4 * sq];
    const float4 rs4 = *(const float4*)&stats[(size_t)BB * HD + gb * HD + 4 * sq];
    const float* xrow = x + gb * TT * HD;
    float* orow = h1out + gb * TT * HD;

    // zero-init hT0 (both buffers) and hT1 ring
    for (int i = tid; i < 2 * 16 * FP / 2; i += 512) ((unsigned*)hT0)[i] = 0u;
    for (int i = tid; i < 16 * 16 * FP / 2; i += 512) ((unsigned*)hT1)[i] = 0u;

    // stage chunk 0
#pragma unroll
    for (int i = 0; i < 4; ++i) {
        const int tau = sth * 4 + i;
        float4 v = *(const float4*)&xrow[(size_t)tau * HD + 4 * sq];
        f16x4 h4 = {(f16)((v.x - mu4.x) * rs4.x), (f16)((v.y - mu4.y) * rs4.y),
                    (f16)((v.z - mu4.z) * rs4.z), (f16)((v.w - mu4.w) * rs4.w)};
        *(f16x4*)&xnb[0][tau][sb * FP + 4 * sq] = h4;
    }

    float cst[4] = {0.f, 0.f, 0.f, 0.f};

    auto PHASE = [&](int t) {
        // B-frags: lane holds B[k = 8*l16+e][n = ln15] -> one 16B read each
        const f16* src1 = &hT0[t & 1][0];
        const f16* src2 = L1w ? &hT1[(t + 15) & 15][0]
                              : &xnb[((t + 1) >> 3) & 1][(t + 1) & 7][0];
        f16x8 B1k0 = *(const f16x8*)&src1[ln15 * FP + 8 * l16];
        f16x8 B1k1 = *(const f16x8*)&src1[ln15 * FP + 32 + 8 * l16];
        f16x8 B2k0 = *(const f16x8*)&src2[ln15 * FP + 8 * l16];
        f16x8 B2k1 = *(const f16x8*)&src2[ln15 * FP + 32 + 8 * l16];
        f32x4 acc[4];
#pragma unroll
        for (int i = 0; i < 4; ++i) {
            acc[i] = bias[i];
            acc[i] = __builtin_amdgcn_mfma_f32_16x16x32_f16(wAf[i][0], B1k0, acc[i], 0, 0, 0);
            acc[i] = __builtin_amdgcn_mfma_f32_16x16x32_f16(wAf[i][1], B1k1, acc[i], 0, 0, 0);
            acc[i] = __builtin_amdgcn_mfma_f32_16x16x32_f16(wBf[i][0], B2k0, acc[i], 0, 0, 0);
            acc[i] = __builtin_amdgcn_mfma_f32_16x16x32_f16(wBf[i][1], B2k1, acc[i], 0, 0, 0);
        }
        // lane-local cell update: batch ln15, feats 16wq+4*l16+{0..3}
        f16* dest = L1w ? &hT1[t & 15][0] : &hT0[(t + 1) & 1][0];
        f16x4 hv;
#pragma unroll
        for (int r = 0; r < 4; ++r) {
            float ai = sigf(acc[0][r]);
            float af = sigf(acc[1][r]);
            float ag = tanhf_fast(acc[2][r]);
            float ao = sigf(acc[3][r]);
            float c = fmaf(af, cst[r], ai * ag);
            cst[r] = c;
            hv[r] = (f16)(ao * tanhf_fast(c));
        }
        *(f16x4*)&dest[ln15 * FP + 16 * wq + 4 * l16] = hv;
    };

    __syncthreads();
    if (!L1w) PHASE(-1);  // layer-0 step 0: reads hT0[1](zeros) + xn(0), writes hT0[0]
    __syncthreads();

    float4 xr[4];
    for (int t = 0; t < TT; ++t) {
        const int tc = t & 7;
        const int cn = (t >> 3) + 1;
        if (tc == 0 && cn < 512) {  // issue next chunk's global loads early
#pragma unroll
            for (int i = 0; i < 4; ++i)
                xr[i] = *(const float4*)&xrow[(size_t)(cn * 8 + sth * 4 + i) * HD + 4 * sq];
        }
        PHASE(t);
        // flush previous chunk's h1 ring slots (written >=4 steps ago)
        if (tc == 3 && t >= 11) {
            const int fch = (t >> 3) - 1;
            const int sbase = (fch & 1) * 8;
#pragma unroll
            for (int i = 0; i < 4; ++i) {
                const int tau = sth * 4 + i;
                f16x4 hvv = *(const f16x4*)&hT1[sbase + tau][sb * FP + 4 * sq];
                float4 o = {(float)hvv[0], (float)hvv[1], (float)hvv[2], (float)hvv[3]};
                *(float4*)&orow[(size_t)(fch * 8 + tau) * HD + 4 * sq] = o;
            }
        }
        // mid-chunk: normalize + LDS-write next chunk (consumed >=2 steps later)
        if (tc == 5 && cn < 512) {
#pragma unroll
            for (int i = 0; i < 4; ++i) {
                const int tau = sth * 4 + i;
                f16x4 h4 = {(f16)((xr[i].x - mu4.x) * rs4.x), (f16)((xr[i].y - mu4.y) * rs4.y),
                            (f16)((xr[i].z - mu4.z) * rs4.z), (f16)((xr[i].w - mu4.w) * rs4.w)};
                *(f16x4*)&xnb[cn & 1][tau][sb * FP + 4 * sq] = h4;
            }
        }
        __syncthreads();
    }
    // epilogue: flush final chunk (slots 8..15 = t 4088..4095)
#pragma unroll
    for (int i = 0; i < 4; ++i) {
        const int tau = sth * 4 + i;
        f16x4 hvv = *(const f16x4*)&hT1[8 + tau][sb * FP + 4 * sq];
        float4 o = {(float)hvv[0], (float)hvv[1], (float)hvv[2], (float)hvv[3]};
        *(float4*)&orow[(size_t)(511 * 8 + tau) * HD + 4 * sq] = o;
    }
}

// ---------------------------------------------------------------------------
// FC + bias + residual, in place on d_out (hout holds h1, rewritten as out).
// ---------------------------------------------------------------------------
__global__ __launch_bounds__(256) void fc_res(float* __restrict__ hout,
                                              const float* __restrict__ x,
                                              const float* __restrict__ Wfc,
                                              const float* __restrict__ bfc) {
    __shared__ __align__(16) float wfc_lds[HD * HD];
    __shared__ float bfc_lds[HD];
    const int tid = threadIdx.x;
#pragma unroll
    for (int i = 0; i < 4; ++i)
        ((float4*)wfc_lds)[tid + 256 * i] = ((const float4*)Wfc)[tid + 256 * i];
    if (tid < HD) bfc_lds[tid] = bfc[tid];

    const size_t row = (size_t)blockIdx.x * 256 + tid;
    float hr[HD];
    {
        const float4* hp = (const float4*)(hout + row * HD);
#pragma unroll
        for (int i = 0; i < 16; ++i) {
            float4 v = hp[i];
            hr[4 * i] = v.x; hr[4 * i + 1] = v.y;
            hr[4 * i + 2] = v.z; hr[4 * i + 3] = v.w;
        }
    }
    __syncthreads();

    const float4* xp = (const float4*)(x + row * HD);
    float4* op = (float4*)(hout + row * HD);
    for (int j4 = 0; j4 < 16; ++j4) {
        float s0 = 0.f, s1 = 0.f, s2 = 0.f, s3 = 0.f;
        const float* w0 = &wfc_lds[(4 * j4 + 0) * HD];
        const float* w1 = &wfc_lds[(4 * j4 + 1) * HD];
        const float* w2 = &wfc_lds[(4 * j4 + 2) * HD];
        const float* w3 = &wfc_lds[(4 * j4 + 3) * HD];
#pragma unroll
        for (int k = 0; k < HD; ++k) {
            s0 = fmaf(w0[k], hr[k], s0);
            s1 = fmaf(w1[k], hr[k], s1);
            s2 = fmaf(w2[k], hr[k], s2);
            s3 = fmaf(w3[k], hr[k], s3);
        }
        float4 xv = xp[j4];
        float4 o;
        o.x = s0 + bfc_lds[4 * j4 + 0] + xv.x;
        o.y = s1 + bfc_lds[4 * j4 + 1] + xv.y;
        o.z = s2 + bfc_lds[4 * j4 + 2] + xv.z;
        o.w = s3 + bfc_lds[4 * j4 + 3] + xv.w;
        op[j4] = o;
    }
}

// ---------------------------------------------------------------------------
extern "C" void kernel_launch(void* const* d_in, const int* in_sizes, int n_in,
                              void* d_out, int out_size, void* d_ws, size_t ws_size,
                              hipStream_t stream) {
    const float* x    = (const float*)d_in[0];
    const float* Wih0 = (const float*)d_in[1];
    const float* Whh0 = (const float*)d_in[2];
    const float* bih0 = (const float*)d_in[3];
    const float* bhh0 = (const float*)d_in[4];
    const float* Wih1 = (const float*)d_in[5];
    const float* Whh1 = (const float*)d_in[6];
    const float* bih1 = (const float*)d_in[7];
    const float* bhh1 = (const float*)d_in[8];
    const float* Wfc  = (const float*)d_in[9];
    const float* bfc  = (const float*)d_in[10];

    float* part  = (float*)d_ws;                 // 2*256*64 floats = 128 KiB
    float* stats = part + 2 * 256 * HD;          // 2*64*64 floats  =  32 KiB
    float* out   = (float*)d_out;

    stats_part<<<256, 256, 0, stream>>>(x, part);
    stats_fin<<<64, 64, 0, stream>>>(part, stats);
    rnn_mfma<<<4, 512, 0, stream>>>(x, Wih0, Whh0, bih0, bhh0,
                                    Wih1, Whh1, bih1, bhh1, stats, out);
    fc_res<<<1024, 256, 0, stream>>>(out, x, Wfc, bfc);
}